// Round 4
// baseline (188.751 us; speedup 1.0000x reference)
//
#include <hip/hip_runtime.h>
#include <hip/hip_bf16.h>
#include <math.h>

// Problem constants (from reference)
#define GRU_H 256
#define H1D   128
#define H2D   64
#define BB    16
#define TT    4000
#define NN    320000   // T * HOP

typedef __attribute__((ext_vector_type(8))) short short8;
typedef __attribute__((ext_vector_type(4))) float f32x4;

// Native bf16 convert (v_cvt_pk_bf16_f32 via compiler; RNE).
static __device__ __forceinline__ unsigned short f2bf(float x) {
    __bf16 b = (__bf16)x;
    return __builtin_bit_cast(unsigned short, b);
}
static __device__ __forceinline__ float bf2f(unsigned short h) {
    return __uint_as_float(((unsigned)h) << 16);
}
// load 8 consecutive floats at p, convert to a bf16 short8 fragment
static __device__ __forceinline__ short8 load_frag8(const float* __restrict__ p) {
    float4 lo = *(const float4*)(p);
    float4 hi = *(const float4*)(p + 4);
    return (short8){(short)f2bf(lo.x), (short)f2bf(lo.y), (short)f2bf(lo.z), (short)f2bf(lo.w),
                    (short)f2bf(hi.x), (short)f2bf(hi.y), (short)f2bf(hi.z), (short)f2bf(hi.w)};
}

// ws layout (uints): [0..1023]   = 64 c-max slots, stride 16 (one/cacheline)
//                    [1024..2047]= 64 e-max slots, stride 16
//                    byte 8192+  = ratio[B*T] floats
#define WS_ESLOT 1024

// ---------------- K1: bf16-MFMA MLP -> ratio[B*T] -----------------------
// R11: direct global->register fragment loads. The old LDS tiles were
// transparent copies (fragment = 8 contiguous floats in global), so the
// global->LDS->register round trip + 16 k-loop barriers bought nothing.
// W1/W2 fragment re-reads across blocks are L2-resident (131KB/32KB);
// gru rows shared by the two wc-waves hit L1 (same CU). LDS now only
// carries the h1/h2 layer handoffs (2 barriers total).
#define H1CH 4608   // 128*36
__global__ __launch_bounds__(256) void mlp_kernel(
    const float* __restrict__ gru, const float* __restrict__ W1,
    const float* __restrict__ b1,  const float* __restrict__ a1p,
    const float* __restrict__ W2,  const float* __restrict__ b2,
    const float* __restrict__ a2p, const float* __restrict__ W3,
    const float* __restrict__ b3,  float* __restrict__ ratio_out,
    unsigned* __restrict__ ws_u)
{
    __shared__ unsigned short smem[27648];   // h1: 18432, h2: 9216
    __shared__ float w3f[64];
    unsigned short* h1s = smem;              // 4 kc-chunks of H1CH
    unsigned short* h2s = smem + 18432;      // 2 chunks of H1CH

    const int t    = threadIdx.x;
    const int wave = t >> 6, lane = t & 63;
    const int lr   = lane & 15, q = lane >> 4;
    const int m0   = blockIdx.x * 128;
    const float a1v = a1p[0], a2v = a2p[0];

    if (blockIdx.x == 0) {               // zero all atomic-max slots
        #pragma unroll
        for (int i = t; i < 2048; i += 256) ws_u[i] = 0u;
    }
    if (t < 64) w3f[t] = W3[2 * H2D + t];         // only row 2 of W3 is live

    // ================= layer 1: h1 = prelu(G @ W1^T + b1) ===============
    const int wr = wave >> 1;
    const int wc = wave & 1;
    f32x4 acc1[4][4];
    #pragma unroll
    for (int mi = 0; mi < 4; ++mi)
        #pragma unroll
        for (int ni = 0; ni < 4; ++ni) acc1[mi][ni] = (f32x4){0.f, 0.f, 0.f, 0.f};

    // per-wave base pointers (rows are fixed across kc)
    const float* ga = gru + (size_t)(m0 + wr * 64 + lr) * GRU_H + q * 8;
    const float* wb = W1  + (size_t)(wc * 64 + lr) * GRU_H + q * 8;

    #pragma unroll
    for (int kc = 0; kc < 8; ++kc) {
        const int k0 = kc * 32;
        short8 af[4], bf[4];
        #pragma unroll
        for (int mi = 0; mi < 4; ++mi)
            af[mi] = load_frag8(ga + (size_t)(mi * 16) * GRU_H + k0);
        #pragma unroll
        for (int ni = 0; ni < 4; ++ni)
            bf[ni] = load_frag8(wb + (size_t)(ni * 16) * GRU_H + k0);
        #pragma unroll
        for (int mi = 0; mi < 4; ++mi)
            #pragma unroll
            for (int ni = 0; ni < 4; ++ni)
                acc1[mi][ni] = __builtin_amdgcn_mfma_f32_16x16x32_bf16(
                    af[mi], bf[ni], acc1[mi][ni], 0, 0, 0);
    }

    #pragma unroll
    for (int ni = 0; ni < 4; ++ni) {
        const int col = wc * 64 + ni * 16 + lr;
        const float bv = b1[col];
        unsigned short* dst = h1s + (col >> 5) * H1CH + (col & 31);
        #pragma unroll
        for (int mi = 0; mi < 4; ++mi) {
            const int rbase = wr * 64 + mi * 16 + q * 4;
            #pragma unroll
            for (int r = 0; r < 4; ++r) {
                float x = acc1[mi][ni][r] + bv;
                x = (x >= 0.f) ? x : a1v * x;
                dst[(rbase + r) * 36] = f2bf(x);
            }
        }
    }
    __syncthreads();

    // ================= layer 2 ==========================================
    const int wr2 = wave >> 1;
    const int wc2 = wave & 1;
    f32x4 acc2[4][2];
    #pragma unroll
    for (int mi = 0; mi < 4; ++mi)
        #pragma unroll
        for (int ni = 0; ni < 2; ++ni) acc2[mi][ni] = (f32x4){0.f, 0.f, 0.f, 0.f};

    const float* w2b = W2 + (size_t)(wc2 * 32 + lr) * H1D + q * 8;

    #pragma unroll
    for (int kc = 0; kc < 4; ++kc) {
        short8 af[4], bf[2];
        #pragma unroll
        for (int mi = 0; mi < 4; ++mi) {
            const unsigned short* p = h1s + kc * H1CH + (wr2 * 64 + mi * 16 + lr) * 36 + q * 8;
            ushort4 lo = *(const ushort4*)(p), hi = *(const ushort4*)(p + 4);
            af[mi] = (short8){(short)lo.x, (short)lo.y, (short)lo.z, (short)lo.w,
                              (short)hi.x, (short)hi.y, (short)hi.z, (short)hi.w};
        }
        #pragma unroll
        for (int ni = 0; ni < 2; ++ni)
            bf[ni] = load_frag8(w2b + (size_t)(ni * 16) * H1D + kc * 32);
        #pragma unroll
        for (int mi = 0; mi < 4; ++mi)
            #pragma unroll
            for (int ni = 0; ni < 2; ++ni)
                acc2[mi][ni] = __builtin_amdgcn_mfma_f32_16x16x32_bf16(
                    af[mi], bf[ni], acc2[mi][ni], 0, 0, 0);
    }

    #pragma unroll
    for (int ni = 0; ni < 2; ++ni) {
        const int col = wc2 * 32 + ni * 16 + lr;
        const float bv = b2[col];
        unsigned short* dst = h2s + (col >> 5) * H1CH + (col & 31);
        #pragma unroll
        for (int mi = 0; mi < 4; ++mi) {
            const int rbase = wr2 * 64 + mi * 16 + q * 4;
            #pragma unroll
            for (int r = 0; r < 4; ++r) {
                float x = acc2[mi][ni][r] + bv;
                x = (x >= 0.f) ? x : a2v * x;
                dst[(rbase + r) * 36] = f2bf(x);
            }
        }
    }
    __syncthreads();

    // ================= layer 3 (p2 only) + softplus + clip ==============
    if (t < 128) {
        float p = b3[2];
        #pragma unroll
        for (int k = 0; k < 64; ++k)
            p = fmaf(bf2f(h2s[(k >> 5) * H1CH + t * 36 + (k & 31)]), w3f[k], p);
        float sp = fmaxf(p, 0.f) + log1pf(expf(-fabsf(p)));
        ratio_out[m0 + t] = fminf(sp + 1.0f, 20.0f);
    }
}

// ---------------- K2: wave-scan IIR compressor --------------------------
// (byte-identical to the R1/R7 passing version)
#define CH     256
#define SEGCH  5
#define SEGLEN (CH * SEGCH)      // 1280
#define SPR    (NN / SEGLEN)     // 250 (exact)
#define NBLK   (BB * SPR / 4)    // 1000

__global__ __launch_bounds__(256, 4) void compress_kernel(
    const float* __restrict__ enh_g, const float* __restrict__ noi_g,
    const float* __restrict__ ratio, float* __restrict__ out,
    unsigned* __restrict__ ws_u)
{
    const int lane = threadIdx.x & 63;
    const int wid  = blockIdx.x * 4 + (threadIdx.x >> 6);   // 0..3999
    const int row  = wid / SPR;
    const int seg  = wid - row * SPR;
    const int s0   = seg * SEGLEN;

    const float* __restrict__ enh  = enh_g + (size_t)row * NN;
    const float* __restrict__ noi  = noi_g + (size_t)row * NN;
    const float* __restrict__ rrow = ratio + row * TT;
    float* __restrict__ orow       = out   + (size_t)row * NN;

    // d_lane = 0.9^(4*lane)
    float d_lane = 1.f;
    if (lane & 1)  d_lane *= 0.65610000f;
    if (lane & 2)  d_lane *= 0.43046721f;
    if (lane & 4)  d_lane *= 0.18530202f;
    if (lane & 8)  d_lane *= 0.034336838f;
    if (lane & 16) d_lane *= 0.0011790185f;
    if (lane & 32) d_lane *= 1.3900845e-06f;

    // ---- preload warmup chunk ----
    const int p0w = s0 - CH + 4 * lane;
    const int pcw = p0w < 0 ? 0 : p0w;
    float4 e_cur = *(const float4*)(enh + pcw);
    float4 x_cur = *(const float4*)(noi + pcw);

    float s_e = 0.f, s_r = 0.f;
    float amax_c = 0.f, amax_e = 0.f;

    #pragma unroll
    for (int ci = 0; ci < SEGCH + 1; ++ci) {
        // prefetch next chunk (always in-bounds)
        float4 e_nxt, x_nxt;
        if (ci < SEGCH) {
            const int pn = s0 - CH + (ci + 1) * CH + 4 * lane;
            e_nxt = *(const float4*)(enh + pn);
            x_nxt = *(const float4*)(noi + pn);
        }

        const int cb = s0 - CH + ci * CH;     // chunk base (wave-uniform)
        const int p0 = cb + 4 * lane;

        // ---- per-sample gains + lane-local partials ----
        float pe[4], pr[4];
        float ge0 = 0.f, gr0 = 0.f;
        float ae = 0.f, ar = 0.f;
        #pragma unroll
        for (int k = 0; k < 4; ++k) {
            const float e   = (&e_cur.x)[k];
            const float x   = (&x_cur.x)[k];
            const float res = x - e;
            const int n  = p0 + k;
            const int nc = n < 0 ? 0 : n;
            float src = fmaf((float)nc + 0.5f, 0.0125f, -0.5f);
            src = fminf(fmaxf(src, 0.f), 3999.f);
            const int   i0 = (int)src;
            const float w  = src - (float)i0;
            const int   i1 = min(i0 + 1, 3999);
            const float r0 = rrow[i0], r1 = rrow[i1];
            const float rr = r0 * (1.f - w) + r1 * w;
            const float rcp_rr = __builtin_amdgcn_rcpf(rr);

            const float env_e = fabsf(e);
            const float gre = (env_e > 0.3f) ? fmaf(env_e - 0.3f, rcp_rr, 0.3f) : env_e;
            const float ge  = fminf(fmaxf(gre * __builtin_amdgcn_rcpf(env_e + 1e-8f), 0.1f), 2.f);
            const float env_r = fabsf(res);
            const float grr = (env_r > 0.1f) ? fmaf(env_r - 0.1f, 2.f * rcp_rr, 0.1f) : env_r;
            const float gr  = fminf(fmaxf(grr * __builtin_amdgcn_rcpf(env_r + 1e-8f), 0.1f), 2.f);

            if (k == 0) { ge0 = ge; gr0 = gr; }
            ae = fmaf(0.9f, ae, 0.1f * ge);
            ar = fmaf(0.9f, ar, 0.1f * gr);
            pe[k] = ae; pr[k] = ar;
        }

        // ---- Kogge-Stone scan over lanes (constant-a: b-only) ----
        float Be = pe[3], Br = pr[3];
        #pragma unroll
        for (int l = 0; l < 6; ++l) {
            const int dlt = 1 << l;
            const float ml = (l == 0) ? 0.65610000f  :
                             (l == 1) ? 0.43046721f  :
                             (l == 2) ? 0.18530202f  :
                             (l == 3) ? 0.034336838f :
                             (l == 4) ? 0.0011790185f : 1.3900845e-06f;
            const float me  = (lane >= dlt) ? ml : 0.f;
            const float bse = __shfl_up(Be, dlt, 64);
            const float bsr = __shfl_up(Br, dlt, 64);
            Be = fmaf(me, bse, Be);
            Br = fmaf(me, bsr, Br);
        }
        float Ee = __shfl_up(Be, 1, 64); if (lane == 0) Ee = 0.f;
        float Er = __shfl_up(Br, 1, 64); if (lane == 0) Er = 0.f;

        // exact reset at global sample 0 (chunk starting at n=0)
        if (cb == 0) { s_e = __shfl(ge0, 0, 64); s_r = __shfl(gr0, 0, 64); }

        const float Se = fmaf(d_lane, s_e, Ee);
        const float Sr = fmaf(d_lane, s_r, Er);

        if (ci > 0) {   // stored chunk (wave-uniform branch)
            float4 o;
            #pragma unroll
            for (int k = 0; k < 4; ++k) {
                const float ck = (k == 0) ? 0.9f : (k == 1) ? 0.81f
                               : (k == 2) ? 0.729f : 0.6561f;
                const float sek = fmaf(ck, Se, pe[k]);
                const float srk = fmaf(ck, Sr, pr[k]);
                const float e   = (&e_cur.x)[k];
                const float res = (&x_cur.x)[k] - e;
                const float c   = fmaf(0.1f * res, srk, e * sek);
                (&o.x)[k] = c;
                amax_c = fmaxf(amax_c, fabsf(c));
                amax_e = fmaxf(amax_e, fabsf(e));
            }
            *(float4*)(orow + p0) = o;
        }

        const float b63e = __shfl(Be, 63, 64);
        const float b63r = __shfl(Br, 63, 64);
        s_e = fmaf(1.9287e-12f, s_e, b63e);
        s_r = fmaf(1.9287e-12f, s_r, b63r);
        e_cur = e_nxt; x_cur = x_nxt;
    }

    // ---- wave -> block -> slot-spread global max reduction ----
    #pragma unroll
    for (int off = 32; off > 0; off >>= 1) {
        amax_c = fmaxf(amax_c, __shfl_xor(amax_c, off, 64));
        amax_e = fmaxf(amax_e, __shfl_xor(amax_e, off, 64));
    }
    __shared__ float red[8];
    const int wv = threadIdx.x >> 6, ln = threadIdx.x & 63;
    if (ln == 0) { red[wv] = amax_c; red[4 + wv] = amax_e; }
    __syncthreads();
    if (threadIdx.x == 0) {
        float mc = fmaxf(fmaxf(red[0], red[1]), fmaxf(red[2], red[3]));
        float me = fmaxf(fmaxf(red[4], red[5]), fmaxf(red[6], red[7]));
        const int slot = (blockIdx.x & 63) * 16;   // one slot per cache line
        atomicMax(ws_u + slot, __float_as_uint(mc));
        atomicMax(ws_u + WS_ESLOT + slot, __float_as_uint(me));
    }
}

// ---------------- K3: reduce slots + in-place normalize -----------------
__global__ __launch_bounds__(256) void scale_kernel(float4* __restrict__ out4,
                                                    const unsigned* __restrict__ ws_u)
{
    const int lane = threadIdx.x & 63;
    float vc = __uint_as_float(ws_u[lane * 16]);
    float ve = __uint_as_float(ws_u[WS_ESLOT + lane * 16]);
    #pragma unroll
    for (int off = 32; off > 0; off >>= 1) {
        vc = fmaxf(vc, __shfl_xor(vc, off, 64));
        ve = fmaxf(ve, __shfl_xor(ve, off, 64));
    }
    const float scale = ve / (vc + 1e-8f);
    const size_t i = (size_t)blockIdx.x * 256 + threadIdx.x;
    float4 v = out4[i];
    v.x *= scale; v.y *= scale; v.z *= scale; v.w *= scale;
    out4[i] = v;
}

extern "C" void kernel_launch(void* const* d_in, const int* in_sizes, int n_in,
                              void* d_out, int out_size, void* d_ws, size_t ws_size,
                              hipStream_t stream) {
    const float* gru = (const float*)d_in[0];
    const float* enh = (const float*)d_in[1];
    const float* noi = (const float*)d_in[2];
    const float* W1  = (const float*)d_in[3];
    const float* b1  = (const float*)d_in[4];
    const float* a1  = (const float*)d_in[5];
    const float* W2  = (const float*)d_in[6];
    const float* b2  = (const float*)d_in[7];
    const float* a2  = (const float*)d_in[8];
    const float* W3  = (const float*)d_in[9];
    const float* b3  = (const float*)d_in[10];
    float* out = (float*)d_out;

    unsigned* ws_u = (unsigned*)d_ws;                 // 2048 uints of max-slots
    float* ratio   = (float*)((char*)d_ws + 8192);    // B*T floats

    mlp_kernel<<<(BB * TT) / 128, 256, 0, stream>>>(gru, W1, b1, a1, W2, b2, a2, W3, b3, ratio, ws_u);
    compress_kernel<<<NBLK, 256, 0, stream>>>(enh, noi, ratio, out, ws_u);
    scale_kernel<<<(BB * NN) / 4 / 256, 256, 0, stream>>>((float4*)out, ws_u);
}

// Round 5
// 186.795 us; speedup vs baseline: 1.0105x; 1.0105x over previous
//
#include <hip/hip_runtime.h>
#include <hip/hip_bf16.h>
#include <math.h>

// Problem constants (from reference)
#define GRU_H 256
#define H1D   128
#define H2D   64
#define BB    16
#define TT    4000
#define NN    320000   // T * HOP

typedef __attribute__((ext_vector_type(8))) short short8;
typedef __attribute__((ext_vector_type(4))) float f32x4;

// Native bf16 convert (v_cvt_pk_bf16_f32 via compiler; RNE).
static __device__ __forceinline__ unsigned short f2bf(float x) {
    __bf16 b = (__bf16)x;
    return __builtin_bit_cast(unsigned short, b);
}
static __device__ __forceinline__ float bf2f(unsigned short h) {
    return __uint_as_float(((unsigned)h) << 16);
}
static __device__ __forceinline__ short8 cvt_frag(float4 lo, float4 hi) {
    return (short8){(short)f2bf(lo.x), (short)f2bf(lo.y), (short)f2bf(lo.z), (short)f2bf(lo.w),
                    (short)f2bf(hi.x), (short)f2bf(hi.y), (short)f2bf(hi.z), (short)f2bf(hi.w)};
}

// ws layout (uints): [0..1023]   = 64 c-max slots, stride 16 (one/cacheline)
//                    [1024..2047]= 64 e-max slots, stride 16
//                    byte 8192+  = ratio[B*T] floats
#define WS_ESLOT 1024

// ---------------- K1: bf16-MFMA MLP -> ratio[B*T] -----------------------
// R12: R11 was latency-bound (MfmaUtil 4%, occ 19%, 47us even when
// L3-resident) because the default VGPR cap (96) left no room to keep
// loads in flight. Fix: __launch_bounds__(256,2) (grid already limits us
// to 2 blocks/CU, so the VGPR headroom is free) + explicit 2-deep
// software pipeline: issue chunk k+1's raw float4 loads before chunk k's
// MFMAs, hiding ~200cy L2 latency under 16 MFMAs + converts.
#define H1CH 4608   // 128*36
__global__ __launch_bounds__(256, 2) void mlp_kernel(
    const float* __restrict__ gru, const float* __restrict__ W1,
    const float* __restrict__ b1,  const float* __restrict__ a1p,
    const float* __restrict__ W2,  const float* __restrict__ b2,
    const float* __restrict__ a2p, const float* __restrict__ W3,
    const float* __restrict__ b3,  float* __restrict__ ratio_out,
    unsigned* __restrict__ ws_u)
{
    __shared__ unsigned short smem[27648];   // h1: 18432, h2: 9216
    __shared__ float w3f[64];
    unsigned short* h1s = smem;              // 4 kc-chunks of H1CH
    unsigned short* h2s = smem + 18432;      // 2 chunks of H1CH

    const int t    = threadIdx.x;
    const int wave = t >> 6, lane = t & 63;
    const int lr   = lane & 15, q = lane >> 4;
    const int m0   = blockIdx.x * 128;
    const float a1v = a1p[0], a2v = a2p[0];

    if (blockIdx.x == 0) {               // zero all atomic-max slots
        #pragma unroll
        for (int i = t; i < 2048; i += 256) ws_u[i] = 0u;
    }
    if (t < 64) w3f[t] = W3[2 * H2D + t];         // only row 2 of W3 is live

    // ================= layer 1: h1 = prelu(G @ W1^T + b1) ===============
    const int wr = wave >> 1;
    const int wc = wave & 1;
    f32x4 acc1[4][4];
    #pragma unroll
    for (int mi = 0; mi < 4; ++mi)
        #pragma unroll
        for (int ni = 0; ni < 4; ++ni) acc1[mi][ni] = (f32x4){0.f, 0.f, 0.f, 0.f};

    // per-wave base pointers (rows are fixed across kc)
    const float* ga = gru + (size_t)(m0 + wr * 64 + lr) * GRU_H + q * 8;
    const float* wb = W1  + (size_t)(wc * 64 + lr) * GRU_H + q * 8;

    // raw fragment registers (2-deep pipeline, chunk k in flight while k-1 computes)
    float4 ra[4][2], rb[4][2];
    #pragma unroll
    for (int mi = 0; mi < 4; ++mi) {
        const float* p = ga + (size_t)(mi * 16) * GRU_H;
        ra[mi][0] = *(const float4*)(p);
        ra[mi][1] = *(const float4*)(p + 4);
    }
    #pragma unroll
    for (int ni = 0; ni < 4; ++ni) {
        const float* p = wb + (size_t)(ni * 16) * GRU_H;
        rb[ni][0] = *(const float4*)(p);
        rb[ni][1] = *(const float4*)(p + 4);
    }

    #pragma unroll 1
    for (int kc = 0; kc < 8; ++kc) {
        // convert current chunk (data already in registers)
        short8 af[4], bf[4];
        #pragma unroll
        for (int mi = 0; mi < 4; ++mi) af[mi] = cvt_frag(ra[mi][0], ra[mi][1]);
        #pragma unroll
        for (int ni = 0; ni < 4; ++ni) bf[ni] = cvt_frag(rb[ni][0], rb[ni][1]);

        // issue next chunk's loads before the MFMAs (latency hides under them)
        if (kc < 7) {
            const int k1 = (kc + 1) * 32;
            #pragma unroll
            for (int mi = 0; mi < 4; ++mi) {
                const float* p = ga + (size_t)(mi * 16) * GRU_H + k1;
                ra[mi][0] = *(const float4*)(p);
                ra[mi][1] = *(const float4*)(p + 4);
            }
            #pragma unroll
            for (int ni = 0; ni < 4; ++ni) {
                const float* p = wb + (size_t)(ni * 16) * GRU_H + k1;
                rb[ni][0] = *(const float4*)(p);
                rb[ni][1] = *(const float4*)(p + 4);
            }
        }

        #pragma unroll
        for (int mi = 0; mi < 4; ++mi)
            #pragma unroll
            for (int ni = 0; ni < 4; ++ni)
                acc1[mi][ni] = __builtin_amdgcn_mfma_f32_16x16x32_bf16(
                    af[mi], bf[ni], acc1[mi][ni], 0, 0, 0);
    }

    #pragma unroll
    for (int ni = 0; ni < 4; ++ni) {
        const int col = wc * 64 + ni * 16 + lr;
        const float bv = b1[col];
        unsigned short* dst = h1s + (col >> 5) * H1CH + (col & 31);
        #pragma unroll
        for (int mi = 0; mi < 4; ++mi) {
            const int rbase = wr * 64 + mi * 16 + q * 4;
            #pragma unroll
            for (int r = 0; r < 4; ++r) {
                float x = acc1[mi][ni][r] + bv;
                x = (x >= 0.f) ? x : a1v * x;
                dst[(rbase + r) * 36] = f2bf(x);
            }
        }
    }
    __syncthreads();

    // ================= layer 2 ==========================================
    const int wr2 = wave >> 1;
    const int wc2 = wave & 1;
    f32x4 acc2[4][2];
    #pragma unroll
    for (int mi = 0; mi < 4; ++mi)
        #pragma unroll
        for (int ni = 0; ni < 2; ++ni) acc2[mi][ni] = (f32x4){0.f, 0.f, 0.f, 0.f};

    const float* w2b = W2 + (size_t)(wc2 * 32 + lr) * H1D + q * 8;

    // prefetch all W2 fragments (4 kc x 2 ni = 8 frags raw = 64 VGPR, acc1 freed)
    float4 rw[4][2][2];
    #pragma unroll
    for (int kc = 0; kc < 4; ++kc)
        #pragma unroll
        for (int ni = 0; ni < 2; ++ni) {
            const float* p = w2b + (size_t)(ni * 16) * H1D + kc * 32;
            rw[kc][ni][0] = *(const float4*)(p);
            rw[kc][ni][1] = *(const float4*)(p + 4);
        }

    #pragma unroll
    for (int kc = 0; kc < 4; ++kc) {
        short8 af[4], bf[2];
        #pragma unroll
        for (int mi = 0; mi < 4; ++mi) {
            const unsigned short* p = h1s + kc * H1CH + (wr2 * 64 + mi * 16 + lr) * 36 + q * 8;
            ushort4 lo = *(const ushort4*)(p), hi = *(const ushort4*)(p + 4);
            af[mi] = (short8){(short)lo.x, (short)lo.y, (short)lo.z, (short)lo.w,
                              (short)hi.x, (short)hi.y, (short)hi.z, (short)hi.w};
        }
        #pragma unroll
        for (int ni = 0; ni < 2; ++ni)
            bf[ni] = cvt_frag(rw[kc][ni][0], rw[kc][ni][1]);
        #pragma unroll
        for (int mi = 0; mi < 4; ++mi)
            #pragma unroll
            for (int ni = 0; ni < 2; ++ni)
                acc2[mi][ni] = __builtin_amdgcn_mfma_f32_16x16x32_bf16(
                    af[mi], bf[ni], acc2[mi][ni], 0, 0, 0);
    }

    #pragma unroll
    for (int ni = 0; ni < 2; ++ni) {
        const int col = wc2 * 32 + ni * 16 + lr;
        const float bv = b2[col];
        unsigned short* dst = h2s + (col >> 5) * H1CH + (col & 31);
        #pragma unroll
        for (int mi = 0; mi < 4; ++mi) {
            const int rbase = wr2 * 64 + mi * 16 + q * 4;
            #pragma unroll
            for (int r = 0; r < 4; ++r) {
                float x = acc2[mi][ni][r] + bv;
                x = (x >= 0.f) ? x : a2v * x;
                dst[(rbase + r) * 36] = f2bf(x);
            }
        }
    }
    __syncthreads();

    // ================= layer 3 (p2 only) + softplus + clip ==============
    if (t < 128) {
        float p = b3[2];
        #pragma unroll
        for (int k = 0; k < 64; ++k)
            p = fmaf(bf2f(h2s[(k >> 5) * H1CH + t * 36 + (k & 31)]), w3f[k], p);
        float sp = fmaxf(p, 0.f) + log1pf(expf(-fabsf(p)));
        ratio_out[m0 + t] = fminf(sp + 1.0f, 20.0f);
    }
}

// ---------------- K2: wave-scan IIR compressor --------------------------
// (byte-identical to the R1/R7 passing version)
#define CH     256
#define SEGCH  5
#define SEGLEN (CH * SEGCH)      // 1280
#define SPR    (NN / SEGLEN)     // 250 (exact)
#define NBLK   (BB * SPR / 4)    // 1000

__global__ __launch_bounds__(256, 4) void compress_kernel(
    const float* __restrict__ enh_g, const float* __restrict__ noi_g,
    const float* __restrict__ ratio, float* __restrict__ out,
    unsigned* __restrict__ ws_u)
{
    const int lane = threadIdx.x & 63;
    const int wid  = blockIdx.x * 4 + (threadIdx.x >> 6);   // 0..3999
    const int row  = wid / SPR;
    const int seg  = wid - row * SPR;
    const int s0   = seg * SEGLEN;

    const float* __restrict__ enh  = enh_g + (size_t)row * NN;
    const float* __restrict__ noi  = noi_g + (size_t)row * NN;
    const float* __restrict__ rrow = ratio + row * TT;
    float* __restrict__ orow       = out   + (size_t)row * NN;

    // d_lane = 0.9^(4*lane)
    float d_lane = 1.f;
    if (lane & 1)  d_lane *= 0.65610000f;
    if (lane & 2)  d_lane *= 0.43046721f;
    if (lane & 4)  d_lane *= 0.18530202f;
    if (lane & 8)  d_lane *= 0.034336838f;
    if (lane & 16) d_lane *= 0.0011790185f;
    if (lane & 32) d_lane *= 1.3900845e-06f;

    // ---- preload warmup chunk ----
    const int p0w = s0 - CH + 4 * lane;
    const int pcw = p0w < 0 ? 0 : p0w;
    float4 e_cur = *(const float4*)(enh + pcw);
    float4 x_cur = *(const float4*)(noi + pcw);

    float s_e = 0.f, s_r = 0.f;
    float amax_c = 0.f, amax_e = 0.f;

    #pragma unroll
    for (int ci = 0; ci < SEGCH + 1; ++ci) {
        // prefetch next chunk (always in-bounds)
        float4 e_nxt, x_nxt;
        if (ci < SEGCH) {
            const int pn = s0 - CH + (ci + 1) * CH + 4 * lane;
            e_nxt = *(const float4*)(enh + pn);
            x_nxt = *(const float4*)(noi + pn);
        }

        const int cb = s0 - CH + ci * CH;     // chunk base (wave-uniform)
        const int p0 = cb + 4 * lane;

        // ---- per-sample gains + lane-local partials ----
        float pe[4], pr[4];
        float ge0 = 0.f, gr0 = 0.f;
        float ae = 0.f, ar = 0.f;
        #pragma unroll
        for (int k = 0; k < 4; ++k) {
            const float e   = (&e_cur.x)[k];
            const float x   = (&x_cur.x)[k];
            const float res = x - e;
            const int n  = p0 + k;
            const int nc = n < 0 ? 0 : n;
            float src = fmaf((float)nc + 0.5f, 0.0125f, -0.5f);
            src = fminf(fmaxf(src, 0.f), 3999.f);
            const int   i0 = (int)src;
            const float w  = src - (float)i0;
            const int   i1 = min(i0 + 1, 3999);
            const float r0 = rrow[i0], r1 = rrow[i1];
            const float rr = r0 * (1.f - w) + r1 * w;
            const float rcp_rr = __builtin_amdgcn_rcpf(rr);

            const float env_e = fabsf(e);
            const float gre = (env_e > 0.3f) ? fmaf(env_e - 0.3f, rcp_rr, 0.3f) : env_e;
            const float ge  = fminf(fmaxf(gre * __builtin_amdgcn_rcpf(env_e + 1e-8f), 0.1f), 2.f);
            const float env_r = fabsf(res);
            const float grr = (env_r > 0.1f) ? fmaf(env_r - 0.1f, 2.f * rcp_rr, 0.1f) : env_r;
            const float gr  = fminf(fmaxf(grr * __builtin_amdgcn_rcpf(env_r + 1e-8f), 0.1f), 2.f);

            if (k == 0) { ge0 = ge; gr0 = gr; }
            ae = fmaf(0.9f, ae, 0.1f * ge);
            ar = fmaf(0.9f, ar, 0.1f * gr);
            pe[k] = ae; pr[k] = ar;
        }

        // ---- Kogge-Stone scan over lanes (constant-a: b-only) ----
        float Be = pe[3], Br = pr[3];
        #pragma unroll
        for (int l = 0; l < 6; ++l) {
            const int dlt = 1 << l;
            const float ml = (l == 0) ? 0.65610000f  :
                             (l == 1) ? 0.43046721f  :
                             (l == 2) ? 0.18530202f  :
                             (l == 3) ? 0.034336838f :
                             (l == 4) ? 0.0011790185f : 1.3900845e-06f;
            const float me  = (lane >= dlt) ? ml : 0.f;
            const float bse = __shfl_up(Be, dlt, 64);
            const float bsr = __shfl_up(Br, dlt, 64);
            Be = fmaf(me, bse, Be);
            Br = fmaf(me, bsr, Br);
        }
        float Ee = __shfl_up(Be, 1, 64); if (lane == 0) Ee = 0.f;
        float Er = __shfl_up(Br, 1, 64); if (lane == 0) Er = 0.f;

        // exact reset at global sample 0 (chunk starting at n=0)
        if (cb == 0) { s_e = __shfl(ge0, 0, 64); s_r = __shfl(gr0, 0, 64); }

        const float Se = fmaf(d_lane, s_e, Ee);
        const float Sr = fmaf(d_lane, s_r, Er);

        if (ci > 0) {   // stored chunk (wave-uniform branch)
            float4 o;
            #pragma unroll
            for (int k = 0; k < 4; ++k) {
                const float ck = (k == 0) ? 0.9f : (k == 1) ? 0.81f
                               : (k == 2) ? 0.729f : 0.6561f;
                const float sek = fmaf(ck, Se, pe[k]);
                const float srk = fmaf(ck, Sr, pr[k]);
                const float e   = (&e_cur.x)[k];
                const float res = (&x_cur.x)[k] - e;
                const float c   = fmaf(0.1f * res, srk, e * sek);
                (&o.x)[k] = c;
                amax_c = fmaxf(amax_c, fabsf(c));
                amax_e = fmaxf(amax_e, fabsf(e));
            }
            *(float4*)(orow + p0) = o;
        }

        const float b63e = __shfl(Be, 63, 64);
        const float b63r = __shfl(Br, 63, 64);
        s_e = fmaf(1.9287e-12f, s_e, b63e);
        s_r = fmaf(1.9287e-12f, s_r, b63r);
        e_cur = e_nxt; x_cur = x_nxt;
    }

    // ---- wave -> block -> slot-spread global max reduction ----
    #pragma unroll
    for (int off = 32; off > 0; off >>= 1) {
        amax_c = fmaxf(amax_c, __shfl_xor(amax_c, off, 64));
        amax_e = fmaxf(amax_e, __shfl_xor(amax_e, off, 64));
    }
    __shared__ float red[8];
    const int wv = threadIdx.x >> 6, ln = threadIdx.x & 63;
    if (ln == 0) { red[wv] = amax_c; red[4 + wv] = amax_e; }
    __syncthreads();
    if (threadIdx.x == 0) {
        float mc = fmaxf(fmaxf(red[0], red[1]), fmaxf(red[2], red[3]));
        float me = fmaxf(fmaxf(red[4], red[5]), fmaxf(red[6], red[7]));
        const int slot = (blockIdx.x & 63) * 16;   // one slot per cache line
        atomicMax(ws_u + slot, __float_as_uint(mc));
        atomicMax(ws_u + WS_ESLOT + slot, __float_as_uint(me));
    }
}

// ---------------- K3: reduce slots + in-place normalize -----------------
__global__ __launch_bounds__(256) void scale_kernel(float4* __restrict__ out4,
                                                    const unsigned* __restrict__ ws_u)
{
    const int lane = threadIdx.x & 63;
    float vc = __uint_as_float(ws_u[lane * 16]);
    float ve = __uint_as_float(ws_u[WS_ESLOT + lane * 16]);
    #pragma unroll
    for (int off = 32; off > 0; off >>= 1) {
        vc = fmaxf(vc, __shfl_xor(vc, off, 64));
        ve = fmaxf(ve, __shfl_xor(ve, off, 64));
    }
    const float scale = ve / (vc + 1e-8f);
    const size_t i = (size_t)blockIdx.x * 256 + threadIdx.x;
    float4 v = out4[i];
    v.x *= scale; v.y *= scale; v.z *= scale; v.w *= scale;
    out4[i] = v;
}

extern "C" void kernel_launch(void* const* d_in, const int* in_sizes, int n_in,
                              void* d_out, int out_size, void* d_ws, size_t ws_size,
                              hipStream_t stream) {
    const float* gru = (const float*)d_in[0];
    const float* enh = (const float*)d_in[1];
    const float* noi = (const float*)d_in[2];
    const float* W1  = (const float*)d_in[3];
    const float* b1  = (const float*)d_in[4];
    const float* a1  = (const float*)d_in[5];
    const float* W2  = (const float*)d_in[6];
    const float* b2  = (const float*)d_in[7];
    const float* a2  = (const float*)d_in[8];
    const float* W3  = (const float*)d_in[9];
    const float* b3  = (const float*)d_in[10];
    float* out = (float*)d_out;

    unsigned* ws_u = (unsigned*)d_ws;                 // 2048 uints of max-slots
    float* ratio   = (float*)((char*)d_ws + 8192);    // B*T floats

    mlp_kernel<<<(BB * TT) / 128, 256, 0, stream>>>(gru, W1, b1, a1, W2, b2, a2, W3, b3, ratio, ws_u);
    compress_kernel<<<NBLK, 256, 0, stream>>>(enh, noi, ratio, out, ws_u);
    scale_kernel<<<(BB * NN) / 4 / 256, 256, 0, stream>>>((float4*)out, ws_u);
}

// Round 6
// 171.531 us; speedup vs baseline: 1.1004x; 1.0890x over previous
//
#include <hip/hip_runtime.h>
#include <hip/hip_bf16.h>
#include <math.h>

// Problem constants (from reference)
#define GRU_H 256
#define H1D   128
#define H2D   64
#define BB    16
#define TT    4000
#define NN    320000   // T * HOP

typedef __attribute__((ext_vector_type(8))) short short8;
typedef __attribute__((ext_vector_type(4))) float f32x4;

// Native bf16 convert (v_cvt_pk_bf16_f32 via compiler; RNE).
static __device__ __forceinline__ unsigned short f2bf(float x) {
    __bf16 b = (__bf16)x;
    return __builtin_bit_cast(unsigned short, b);
}
static __device__ __forceinline__ float bf2f(unsigned short h) {
    return __uint_as_float(((unsigned)h) << 16);
}
static __device__ __forceinline__ ushort4 cvt4(float4 v) {
    return (ushort4){f2bf(v.x), f2bf(v.y), f2bf(v.z), f2bf(v.w)};
}

// ws layout (uints): [0..1023]   = 64 c-max slots, stride 16 (one/cacheline)
//                    [1024..2047]= 64 e-max slots, stride 16
//                    byte 8192+  = ratio[B*T] floats
#define WS_ESLOT 1024

// ---------------- K1: bf16-MFMA MLP -> ratio[B*T] -----------------------
// R13: back to the R0 LDS-staged structure (proven 173us total) with ONE
// change: stage loads are issued one kc-chunk EARLY into registers (reg
// double-buffer). R0 exposed the global-load latency between the two
// barriers each chunk (load -> LDS write -> barrier -> MFMA serialized);
// now chunk k+1's loads are issued right after chunk k's LDS writes and
// only consumed after the next barrier, so their latency drains under the
// 16-MFMA phase. R11/R12 failed because nothing forced early issue for
// reg-consumed loads; here the consumer is an LDS write on the far side
// of a barrier, which the compiler cannot hoist the load past its wait.
#define H1CH 4608   // 128*36
#define W2CH 2304   // 64*36
__global__ __launch_bounds__(256, 2) void mlp_kernel(
    const float* __restrict__ gru, const float* __restrict__ W1,
    const float* __restrict__ b1,  const float* __restrict__ a1p,
    const float* __restrict__ W2,  const float* __restrict__ b2,
    const float* __restrict__ a2p, const float* __restrict__ W3,
    const float* __restrict__ b3,  float* __restrict__ ratio_out,
    unsigned* __restrict__ ws_u)
{
    __shared__ unsigned short smem[36864];
    __shared__ float w3f[64];
    unsigned short* As  = smem;
    unsigned short* Bs  = smem + 4608;
    unsigned short* h2s = smem;          // overlays As/Bs (safe: after layer 1)
    unsigned short* h1s = smem + 9216;
    unsigned short* W2s = smem + 27648;

    const int t    = threadIdx.x;
    const int wave = t >> 6, lane = t & 63;
    const int lr   = lane & 15, q = lane >> 4;
    const int m0   = blockIdx.x * 128;
    const float a1v = a1p[0], a2v = a2p[0];

    if (blockIdx.x == 0) {               // zero all atomic-max slots
        #pragma unroll
        for (int i = t; i < 2048; i += 256) ws_u[i] = 0u;
    }
    if (t < 64) w3f[t] = W3[2 * H2D + t];         // only row 2 of W3 is live

    // ================= layer 1: h1 = prelu(G @ W1^T + b1) ===============
    const int wr = wave >> 1;
    const int wc = wave & 1;
    f32x4 acc1[4][4];
    #pragma unroll
    for (int mi = 0; mi < 4; ++mi)
        #pragma unroll
        for (int ni = 0; ni < 4; ++ni) acc1[mi][ni] = (f32x4){0.f, 0.f, 0.f, 0.f};

    // staging addresses for this thread (row/c4 fixed across kc)
    const int srow[4] = { (t + 0)   >> 3, (t + 256) >> 3,
                          (t + 512) >> 3, (t + 768) >> 3 };
    const int sc4 = t & 7;

    // prologue: load chunk 0 into registers
    float4 rg[4], rw[4];
    #pragma unroll
    for (int it = 0; it < 4; ++it) {
        rg[it] = *(const float4*)(gru + (size_t)(m0 + srow[it]) * GRU_H + sc4 * 4);
        rw[it] = *(const float4*)(W1  + (size_t)srow[it] * GRU_H + sc4 * 4);
    }

    #pragma unroll 1
    for (int kc = 0; kc < 8; ++kc) {
        __syncthreads();                          // prev readers done
        #pragma unroll
        for (int it = 0; it < 4; ++it) {
            *(ushort4*)(As + srow[it] * 36 + sc4 * 4) = cvt4(rg[it]);
            *(ushort4*)(Bs + srow[it] * 36 + sc4 * 4) = cvt4(rw[it]);
        }
        // issue next chunk's loads now; consumed only after next barrier
        float4 ng[4], nw[4];
        if (kc < 7) {
            const int k1 = (kc + 1) * 32;
            #pragma unroll
            for (int it = 0; it < 4; ++it) {
                ng[it] = *(const float4*)(gru + (size_t)(m0 + srow[it]) * GRU_H + k1 + sc4 * 4);
                nw[it] = *(const float4*)(W1  + (size_t)srow[it] * GRU_H + k1 + sc4 * 4);
            }
        }
        __syncthreads();                          // tiles ready

        short8 af[4], bf[4];
        #pragma unroll
        for (int mi = 0; mi < 4; ++mi) {
            const unsigned short* p = As + (wr * 64 + mi * 16 + lr) * 36 + q * 8;
            ushort4 lo = *(const ushort4*)(p), hi = *(const ushort4*)(p + 4);
            af[mi] = (short8){(short)lo.x, (short)lo.y, (short)lo.z, (short)lo.w,
                              (short)hi.x, (short)hi.y, (short)hi.z, (short)hi.w};
        }
        #pragma unroll
        for (int ni = 0; ni < 4; ++ni) {
            const unsigned short* p = Bs + (wc * 64 + ni * 16 + lr) * 36 + q * 8;
            ushort4 lo = *(const ushort4*)(p), hi = *(const ushort4*)(p + 4);
            bf[ni] = (short8){(short)lo.x, (short)lo.y, (short)lo.z, (short)lo.w,
                              (short)hi.x, (short)hi.y, (short)hi.z, (short)hi.w};
        }
        #pragma unroll
        for (int mi = 0; mi < 4; ++mi)
            #pragma unroll
            for (int ni = 0; ni < 4; ++ni)
                acc1[mi][ni] = __builtin_amdgcn_mfma_f32_16x16x32_bf16(
                    af[mi], bf[ni], acc1[mi][ni], 0, 0, 0);

        if (kc < 7) {
            #pragma unroll
            for (int it = 0; it < 4; ++it) { rg[it] = ng[it]; rw[it] = nw[it]; }
        }
    }

    #pragma unroll
    for (int ni = 0; ni < 4; ++ni) {
        const int col = wc * 64 + ni * 16 + lr;
        const float bv = b1[col];
        unsigned short* dst = h1s + (col >> 5) * H1CH + (col & 31);
        #pragma unroll
        for (int mi = 0; mi < 4; ++mi) {
            const int rbase = wr * 64 + mi * 16 + q * 4;
            #pragma unroll
            for (int r = 0; r < 4; ++r) {
                float x = acc1[mi][ni][r] + bv;
                x = (x >= 0.f) ? x : a1v * x;
                dst[(rbase + r) * 36] = f2bf(x);
            }
        }
    }
    #pragma unroll
    for (int it = 0; it < 8; ++it) {
        const int idx = t + 256 * it;
        const int row = idx >> 5, c4 = idx & 31;
        float4 w = *(const float4*)(W2 + (size_t)row * H1D + c4 * 4);
        *(ushort4*)(W2s + (c4 >> 3) * W2CH + row * 36 + (c4 & 7) * 4) = cvt4(w);
    }
    __syncthreads();

    // ================= layer 2 ==========================================
    const int wr2 = wave >> 1;
    const int wc2 = wave & 1;
    f32x4 acc2[4][2];
    #pragma unroll
    for (int mi = 0; mi < 4; ++mi)
        #pragma unroll
        for (int ni = 0; ni < 2; ++ni) acc2[mi][ni] = (f32x4){0.f, 0.f, 0.f, 0.f};

    #pragma unroll
    for (int kc = 0; kc < 4; ++kc) {
        short8 af[4], bf[2];
        #pragma unroll
        for (int mi = 0; mi < 4; ++mi) {
            const unsigned short* p = h1s + kc * H1CH + (wr2 * 64 + mi * 16 + lr) * 36 + q * 8;
            ushort4 lo = *(const ushort4*)(p), hi = *(const ushort4*)(p + 4);
            af[mi] = (short8){(short)lo.x, (short)lo.y, (short)lo.z, (short)lo.w,
                              (short)hi.x, (short)hi.y, (short)hi.z, (short)hi.w};
        }
        #pragma unroll
        for (int ni = 0; ni < 2; ++ni) {
            const unsigned short* p = W2s + kc * W2CH + (wc2 * 32 + ni * 16 + lr) * 36 + q * 8;
            ushort4 lo = *(const ushort4*)(p), hi = *(const ushort4*)(p + 4);
            bf[ni] = (short8){(short)lo.x, (short)lo.y, (short)lo.z, (short)lo.w,
                              (short)hi.x, (short)hi.y, (short)hi.z, (short)hi.w};
        }
        #pragma unroll
        for (int mi = 0; mi < 4; ++mi)
            #pragma unroll
            for (int ni = 0; ni < 2; ++ni)
                acc2[mi][ni] = __builtin_amdgcn_mfma_f32_16x16x32_bf16(
                    af[mi], bf[ni], acc2[mi][ni], 0, 0, 0);
    }

    #pragma unroll
    for (int ni = 0; ni < 2; ++ni) {
        const int col = wc2 * 32 + ni * 16 + lr;
        const float bv = b2[col];
        unsigned short* dst = h2s + (col >> 5) * H1CH + (col & 31);
        #pragma unroll
        for (int mi = 0; mi < 4; ++mi) {
            const int rbase = wr2 * 64 + mi * 16 + q * 4;
            #pragma unroll
            for (int r = 0; r < 4; ++r) {
                float x = acc2[mi][ni][r] + bv;
                x = (x >= 0.f) ? x : a2v * x;
                dst[(rbase + r) * 36] = f2bf(x);
            }
        }
    }
    __syncthreads();

    // ================= layer 3 (p2 only) + softplus + clip ==============
    if (t < 128) {
        float p = b3[2];
        #pragma unroll
        for (int k = 0; k < 64; ++k)
            p = fmaf(bf2f(h2s[(k >> 5) * H1CH + t * 36 + (k & 31)]), w3f[k], p);
        float sp = fmaxf(p, 0.f) + log1pf(expf(-fabsf(p)));
        ratio_out[m0 + t] = fminf(sp + 1.0f, 20.0f);
    }
}

// ---------------- K2: wave-scan IIR compressor --------------------------
// (byte-identical to the R1/R7 passing version)
#define CH     256
#define SEGCH  5
#define SEGLEN (CH * SEGCH)      // 1280
#define SPR    (NN / SEGLEN)     // 250 (exact)
#define NBLK   (BB * SPR / 4)    // 1000

__global__ __launch_bounds__(256, 4) void compress_kernel(
    const float* __restrict__ enh_g, const float* __restrict__ noi_g,
    const float* __restrict__ ratio, float* __restrict__ out,
    unsigned* __restrict__ ws_u)
{
    const int lane = threadIdx.x & 63;
    const int wid  = blockIdx.x * 4 + (threadIdx.x >> 6);   // 0..3999
    const int row  = wid / SPR;
    const int seg  = wid - row * SPR;
    const int s0   = seg * SEGLEN;

    const float* __restrict__ enh  = enh_g + (size_t)row * NN;
    const float* __restrict__ noi  = noi_g + (size_t)row * NN;
    const float* __restrict__ rrow = ratio + row * TT;
    float* __restrict__ orow       = out   + (size_t)row * NN;

    // d_lane = 0.9^(4*lane)
    float d_lane = 1.f;
    if (lane & 1)  d_lane *= 0.65610000f;
    if (lane & 2)  d_lane *= 0.43046721f;
    if (lane & 4)  d_lane *= 0.18530202f;
    if (lane & 8)  d_lane *= 0.034336838f;
    if (lane & 16) d_lane *= 0.0011790185f;
    if (lane & 32) d_lane *= 1.3900845e-06f;

    // ---- preload warmup chunk ----
    const int p0w = s0 - CH + 4 * lane;
    const int pcw = p0w < 0 ? 0 : p0w;
    float4 e_cur = *(const float4*)(enh + pcw);
    float4 x_cur = *(const float4*)(noi + pcw);

    float s_e = 0.f, s_r = 0.f;
    float amax_c = 0.f, amax_e = 0.f;

    #pragma unroll
    for (int ci = 0; ci < SEGCH + 1; ++ci) {
        // prefetch next chunk (always in-bounds)
        float4 e_nxt, x_nxt;
        if (ci < SEGCH) {
            const int pn = s0 - CH + (ci + 1) * CH + 4 * lane;
            e_nxt = *(const float4*)(enh + pn);
            x_nxt = *(const float4*)(noi + pn);
        }

        const int cb = s0 - CH + ci * CH;     // chunk base (wave-uniform)
        const int p0 = cb + 4 * lane;

        // ---- per-sample gains + lane-local partials ----
        float pe[4], pr[4];
        float ge0 = 0.f, gr0 = 0.f;
        float ae = 0.f, ar = 0.f;
        #pragma unroll
        for (int k = 0; k < 4; ++k) {
            const float e   = (&e_cur.x)[k];
            const float x   = (&x_cur.x)[k];
            const float res = x - e;
            const int n  = p0 + k;
            const int nc = n < 0 ? 0 : n;
            float src = fmaf((float)nc + 0.5f, 0.0125f, -0.5f);
            src = fminf(fmaxf(src, 0.f), 3999.f);
            const int   i0 = (int)src;
            const float w  = src - (float)i0;
            const int   i1 = min(i0 + 1, 3999);
            const float r0 = rrow[i0], r1 = rrow[i1];
            const float rr = r0 * (1.f - w) + r1 * w;
            const float rcp_rr = __builtin_amdgcn_rcpf(rr);

            const float env_e = fabsf(e);
            const float gre = (env_e > 0.3f) ? fmaf(env_e - 0.3f, rcp_rr, 0.3f) : env_e;
            const float ge  = fminf(fmaxf(gre * __builtin_amdgcn_rcpf(env_e + 1e-8f), 0.1f), 2.f);
            const float env_r = fabsf(res);
            const float grr = (env_r > 0.1f) ? fmaf(env_r - 0.1f, 2.f * rcp_rr, 0.1f) : env_r;
            const float gr  = fminf(fmaxf(grr * __builtin_amdgcn_rcpf(env_r + 1e-8f), 0.1f), 2.f);

            if (k == 0) { ge0 = ge; gr0 = gr; }
            ae = fmaf(0.9f, ae, 0.1f * ge);
            ar = fmaf(0.9f, ar, 0.1f * gr);
            pe[k] = ae; pr[k] = ar;
        }

        // ---- Kogge-Stone scan over lanes (constant-a: b-only) ----
        float Be = pe[3], Br = pr[3];
        #pragma unroll
        for (int l = 0; l < 6; ++l) {
            const int dlt = 1 << l;
            const float ml = (l == 0) ? 0.65610000f  :
                             (l == 1) ? 0.43046721f  :
                             (l == 2) ? 0.18530202f  :
                             (l == 3) ? 0.034336838f :
                             (l == 4) ? 0.0011790185f : 1.3900845e-06f;
            const float me  = (lane >= dlt) ? ml : 0.f;
            const float bse = __shfl_up(Be, dlt, 64);
            const float bsr = __shfl_up(Br, dlt, 64);
            Be = fmaf(me, bse, Be);
            Br = fmaf(me, bsr, Br);
        }
        float Ee = __shfl_up(Be, 1, 64); if (lane == 0) Ee = 0.f;
        float Er = __shfl_up(Br, 1, 64); if (lane == 0) Er = 0.f;

        // exact reset at global sample 0 (chunk starting at n=0)
        if (cb == 0) { s_e = __shfl(ge0, 0, 64); s_r = __shfl(gr0, 0, 64); }

        const float Se = fmaf(d_lane, s_e, Ee);
        const float Sr = fmaf(d_lane, s_r, Er);

        if (ci > 0) {   // stored chunk (wave-uniform branch)
            float4 o;
            #pragma unroll
            for (int k = 0; k < 4; ++k) {
                const float ck = (k == 0) ? 0.9f : (k == 1) ? 0.81f
                               : (k == 2) ? 0.729f : 0.6561f;
                const float sek = fmaf(ck, Se, pe[k]);
                const float srk = fmaf(ck, Sr, pr[k]);
                const float e   = (&e_cur.x)[k];
                const float res = (&x_cur.x)[k] - e;
                const float c   = fmaf(0.1f * res, srk, e * sek);
                (&o.x)[k] = c;
                amax_c = fmaxf(amax_c, fabsf(c));
                amax_e = fmaxf(amax_e, fabsf(e));
            }
            *(float4*)(orow + p0) = o;
        }

        const float b63e = __shfl(Be, 63, 64);
        const float b63r = __shfl(Br, 63, 64);
        s_e = fmaf(1.9287e-12f, s_e, b63e);
        s_r = fmaf(1.9287e-12f, s_r, b63r);
        e_cur = e_nxt; x_cur = x_nxt;
    }

    // ---- wave -> block -> slot-spread global max reduction ----
    #pragma unroll
    for (int off = 32; off > 0; off >>= 1) {
        amax_c = fmaxf(amax_c, __shfl_xor(amax_c, off, 64));
        amax_e = fmaxf(amax_e, __shfl_xor(amax_e, off, 64));
    }
    __shared__ float red[8];
    const int wv = threadIdx.x >> 6, ln = threadIdx.x & 63;
    if (ln == 0) { red[wv] = amax_c; red[4 + wv] = amax_e; }
    __syncthreads();
    if (threadIdx.x == 0) {
        float mc = fmaxf(fmaxf(red[0], red[1]), fmaxf(red[2], red[3]));
        float me = fmaxf(fmaxf(red[4], red[5]), fmaxf(red[6], red[7]));
        const int slot = (blockIdx.x & 63) * 16;   // one slot per cache line
        atomicMax(ws_u + slot, __float_as_uint(mc));
        atomicMax(ws_u + WS_ESLOT + slot, __float_as_uint(me));
    }
}

// ---------------- K3: reduce slots + in-place normalize -----------------
__global__ __launch_bounds__(256) void scale_kernel(float4* __restrict__ out4,
                                                    const unsigned* __restrict__ ws_u)
{
    const int lane = threadIdx.x & 63;
    float vc = __uint_as_float(ws_u[lane * 16]);
    float ve = __uint_as_float(ws_u[WS_ESLOT + lane * 16]);
    #pragma unroll
    for (int off = 32; off > 0; off >>= 1) {
        vc = fmaxf(vc, __shfl_xor(vc, off, 64));
        ve = fmaxf(ve, __shfl_xor(ve, off, 64));
    }
    const float scale = ve / (vc + 1e-8f);
    const size_t i = (size_t)blockIdx.x * 256 + threadIdx.x;
    float4 v = out4[i];
    v.x *= scale; v.y *= scale; v.z *= scale; v.w *= scale;
    out4[i] = v;
}

extern "C" void kernel_launch(void* const* d_in, const int* in_sizes, int n_in,
                              void* d_out, int out_size, void* d_ws, size_t ws_size,
                              hipStream_t stream) {
    const float* gru = (const float*)d_in[0];
    const float* enh = (const float*)d_in[1];
    const float* noi = (const float*)d_in[2];
    const float* W1  = (const float*)d_in[3];
    const float* b1  = (const float*)d_in[4];
    const float* a1  = (const float*)d_in[5];
    const float* W2  = (const float*)d_in[6];
    const float* b2  = (const float*)d_in[7];
    const float* a2  = (const float*)d_in[8];
    const float* W3  = (const float*)d_in[9];
    const float* b3  = (const float*)d_in[10];
    float* out = (float*)d_out;

    unsigned* ws_u = (unsigned*)d_ws;                 // 2048 uints of max-slots
    float* ratio   = (float*)((char*)d_ws + 8192);    // B*T floats

    mlp_kernel<<<(BB * TT) / 128, 256, 0, stream>>>(gru, W1, b1, a1, W2, b2, a2, W3, b3, ratio, ws_u);
    compress_kernel<<<NBLK, 256, 0, stream>>>(enh, noi, ratio, out, ws_u);
    scale_kernel<<<(BB * NN) / 4 / 256, 256, 0, stream>>>((float4*)out, ws_u);
}